// Round 1
// baseline (728.576 us; speedup 1.0000x reference)
//
#include <hip/hip_runtime.h>
#include <hip/hip_bf16.h>

// Problem constants
constexpr int Bb = 64;    // batch
constexpr int Cc = 32;    // capsules (softmax axis)
constexpr int Nn = 1152;  // routes
constexpr int Oo = 64;    // out channels
constexpr int Ii = 64;    // in channels
constexpr int NCHUNK = 16;            // n-chunks for route_pass
constexpr int CHN = Nn / NCHUNK;      // 72 n per chunk

// ---------------- GEMM: u[b][c][n][o] = sum_i w[c][n][o][i] * x[b][n][i] ----
// Block: one (n, c). Computes full 64(b) x 64(o) tile, K=64.
// LDS: A = x rows (b, K-contig), Bm = w rows (o, K-contig), XOR-swizzled f4.
__global__ __launch_bounds__(256) void gemm_uhat(const float* __restrict__ x,
                                                 const float* __restrict__ w,
                                                 float* __restrict__ u) {
    const int n = blockIdx.x;
    const int c = blockIdx.y;
    __shared__ float4 ax[64 * 16];  // x tile, rows = b
    __shared__ float4 bw[64 * 16];  // w tile, rows = o
    const int t = threadIdx.x;

    // Stage tiles: 64 rows x 16 float4 each; 4 iters x 256 threads.
    for (int it = 0; it < 4; ++it) {
        int g = it * 256 + t;
        int r = g >> 4;        // row
        int q = g & 15;        // f4 col
        int sw = q ^ ((r >> 2) & 7);
        float4 vx = *(const float4*)(x + ((size_t)r * Nn + n) * Ii + q * 4);
        ax[r * 16 + sw] = vx;
        float4 vw = *(const float4*)(w + (((size_t)c * Nn + n) * Oo + r) * Ii + q * 4);
        bw[r * 16 + sw] = vw;
    }
    __syncthreads();

    const int ty = t >> 4;   // 0..15 -> b rows 4*ty..4*ty+3
    const int tx = t & 15;   // 0..15 -> o cols 4*tx..4*tx+3
    float acc[4][4];
#pragma unroll
    for (int j = 0; j < 4; ++j)
#pragma unroll
        for (int k = 0; k < 4; ++k) acc[j][k] = 0.f;

#pragma unroll
    for (int i0 = 0; i0 < 16; ++i0) {  // f4 index along K
        float4 a4[4], b4[4];
#pragma unroll
        for (int j = 0; j < 4; ++j) a4[j] = ax[(4 * ty + j) * 16 + (i0 ^ (ty & 7))];
#pragma unroll
        for (int k = 0; k < 4; ++k) b4[k] = bw[(4 * tx + k) * 16 + (i0 ^ (tx & 7))];
#pragma unroll
        for (int j = 0; j < 4; ++j)
#pragma unroll
            for (int k = 0; k < 4; ++k) {
                acc[j][k] = fmaf(a4[j].x, b4[k].x, acc[j][k]);
                acc[j][k] = fmaf(a4[j].y, b4[k].y, acc[j][k]);
                acc[j][k] = fmaf(a4[j].z, b4[k].z, acc[j][k]);
                acc[j][k] = fmaf(a4[j].w, b4[k].w, acc[j][k]);
            }
    }

    // Store u[b][c][n][o]: per j a float4 along o (fully coalesced across tx).
#pragma unroll
    for (int j = 0; j < 4; ++j) {
        int bb = 4 * ty + j;
        float4 v = make_float4(acc[j][0], acc[j][1], acc[j][2], acc[j][3]);
        *(float4*)(u + (((size_t)bb * Cc + c) * Nn + n) * Oo + 4 * tx) = v;
    }
}

// ---------------- iter 0: c = 1/32 exactly; s0 = mean_n u; V = squash(s0) ---
__device__ __forceinline__ float squash_elem(float s) {
    float sq = s * s;
    return (sq / (1.f + sq)) * s / sqrtf(sq + 1e-8f);
}

__global__ __launch_bounds__(256) void reduce0_squash(const float* __restrict__ u,
                                                      float* __restrict__ V) {
    const int b = blockIdx.x, c = blockIdx.y;
    const int t = threadIdx.x;
    const int o = t & 63, part = t >> 6;
    const float* base = u + ((size_t)(b * Cc + c) * Nn) * Oo + o;
    float s = 0.f;
    for (int n = part; n < Nn; n += 4) s += base[(size_t)n * Oo];
    __shared__ float red[4][64];
    red[part][o] = s;
    __syncthreads();
    if (t < 64) {
        float ss = red[0][t] + red[1][t] + red[2][t] + red[3][t];
        ss *= (1.0f / 32.0f);
        V[(size_t)(b * Cc + c) * Oo + t] = squash_elem(ss);
    }
}

// ---------------- routing pass: s[b,c,o] = sum_n softmax_c(u*V) * u ---------
// Grid (B, NCHUNK). 4 waves/block, lane = o, each wave strides n within chunk.
__global__ __launch_bounds__(256) void route_pass(const float* __restrict__ u,
                                                  const float* __restrict__ V,
                                                  float* __restrict__ part) {
    const int b = blockIdx.x;
    const int ch = blockIdx.y;
    const int t = threadIdx.x;
    const int lane = t & 63, wv = t >> 6;

    __shared__ float sV[Cc * 64];
    for (int idx = t; idx < Cc * 64; idx += 256) sV[idx] = V[(size_t)b * Cc * Oo + idx];
    __syncthreads();

    float vreg[Cc];
#pragma unroll
    for (int c = 0; c < Cc; ++c) vreg[c] = sV[c * 64 + lane];

    float acc[Cc];
#pragma unroll
    for (int c = 0; c < Cc; ++c) acc[c] = 0.f;

    const float* ub = u + (size_t)b * Cc * Nn * Oo + lane;
    const int nend = ch * CHN + CHN;
    for (int n = ch * CHN + wv; n < nend; n += 4) {
        float uv[Cc], l[Cc];
        float m = -1e30f;
#pragma unroll
        for (int c = 0; c < Cc; ++c) uv[c] = ub[((size_t)c * Nn + n) * Oo];
#pragma unroll
        for (int c = 0; c < Cc; ++c) {
            l[c] = uv[c] * vreg[c];
            m = fmaxf(m, l[c]);
        }
        float Z = 0.f;
#pragma unroll
        for (int c = 0; c < Cc; ++c) {
            l[c] = __expf(l[c] - m);
            Z += l[c];
        }
        float rz = 1.f / Z;
#pragma unroll
        for (int c = 0; c < Cc; ++c) acc[c] = fmaf(l[c] * rz, uv[c], acc[c]);
    }

    __shared__ float sacc[4][Cc][64];
#pragma unroll
    for (int c = 0; c < Cc; ++c) sacc[wv][c][lane] = acc[c];
    __syncthreads();
    for (int idx = t; idx < Cc * 64; idx += 256) {
        int c = idx >> 6, o = idx & 63;
        float ssum = sacc[0][c][o] + sacc[1][c][o] + sacc[2][c][o] + sacc[3][c][o];
        part[(((size_t)b * NCHUNK + ch) * Cc + c) * 64 + o] = ssum;
    }
}

// ---------------- squash + V update / final output --------------------------
__global__ void squash_update(const float* __restrict__ part, float* __restrict__ V,
                              float* __restrict__ out, int write_out) {
    const int b = blockIdx.x, c = blockIdx.y;
    const int o = threadIdx.x;  // 64 threads
    float s = 0.f;
    for (int ch = 0; ch < NCHUNK; ++ch)
        s += part[(((size_t)b * NCHUNK + ch) * Cc + c) * 64 + o];
    float v = squash_elem(s);
    size_t idx = (size_t)(b * Cc + c) * Oo + o;
    if (write_out) out[idx] = v;   // final iteration: v2 -> output
    else V[idx] += v;              // V = v0 + v1 before last pass
}

extern "C" void kernel_launch(void* const* d_in, const int* in_sizes, int n_in,
                              void* d_out, int out_size, void* d_ws, size_t ws_size,
                              hipStream_t stream) {
    const float* x = (const float*)d_in[0];          // [64,1152,64]
    const float* w = (const float*)d_in[1];          // [32,1152,64,64]
    float* out = (float*)d_out;                      // [64,32,64]

    float* u = (float*)d_ws;                                      // 603,979,776 B
    float* V = u + (size_t)Bb * Cc * Nn * Oo;                     // 524,288 B
    float* part = V + (size_t)Bb * Cc * Oo;                       // 8,388,608 B

    gemm_uhat<<<dim3(Nn, Cc), 256, 0, stream>>>(x, w, u);
    reduce0_squash<<<dim3(Bb, Cc), 256, 0, stream>>>(u, V);
    route_pass<<<dim3(Bb, NCHUNK), 256, 0, stream>>>(u, V, part);
    squash_update<<<dim3(Bb, Cc), 64, 0, stream>>>(part, V, out, 0);
    route_pass<<<dim3(Bb, NCHUNK), 256, 0, stream>>>(u, V, part);
    squash_update<<<dim3(Bb, Cc), 64, 0, stream>>>(part, V, out, 1);
}

// Round 3
// 509.009 us; speedup vs baseline: 1.4314x; 1.4314x over previous
//
#include <hip/hip_runtime.h>
#include <hip/hip_bf16.h>

typedef short short8v __attribute__((ext_vector_type(8)));
typedef float float4v __attribute__((ext_vector_type(4)));

constexpr int Bb = 64;    // batch
constexpr int Cc = 32;    // capsules (softmax axis)
constexpr int Nn = 1152;  // routes
constexpr int Oo = 64;    // out channels
constexpr int Ii = 64;    // in channels
constexpr int NCH = 32;   // n-chunks (grid.x)
constexpr int CHN = 36;   // n per chunk
constexpr int OT  = 16;   // o-tiles (grid.y)
// per-n w slice: 128 cols (c*4+o_local) x 64 i

__device__ __forceinline__ unsigned short bf16_rne(float f) {
    unsigned u = __float_as_uint(f);
    u += 0x7FFFu + ((u >> 16) & 1u);
    return (unsigned short)(u >> 16);
}
__device__ __forceinline__ float bf16_f(unsigned short h) {
    return __uint_as_float(((unsigned)h) << 16);
}
__device__ __forceinline__ float squash_elem(float s) {
    float sq = s * s;
    return (sq / (1.f + sq)) * s / sqrtf(sq + 1e-8f);
}

// ---- pre-split x into hi/lo bf16 planes (one-time, 38 MB traffic) ----------
__global__ __launch_bounds__(256) void prep_x(const float* __restrict__ x,
                                              unsigned short* __restrict__ xh,
                                              unsigned short* __restrict__ xl) {
    size_t g = (size_t)blockIdx.x * 256 + threadIdx.x;  // one float4 per thread
    float4 v = ((const float4*)x)[g];
    float a[4] = {v.x, v.y, v.z, v.w};
    ushort4 H, L;
    unsigned short* hp = (unsigned short*)&H;
    unsigned short* lp = (unsigned short*)&L;
#pragma unroll
    for (int e = 0; e < 4; ++e) {
        unsigned short hb = bf16_rne(a[e]);
        hp[e] = hb;
        lp[e] = bf16_rne(a[e] - bf16_f(hb));
    }
    ((ushort4*)xh)[g] = H;
    ((ushort4*)xl)[g] = L;
}

// ---- fused pass: recompute u via split-bf16 MFMA, route, partial-reduce ----
// MODE 0: acc += u (iter-0 uniform weights; /32 applied in reduce)
// MODE 1: acc += softmax_c(u*V) * u
template <int MODE>
__global__ __launch_bounds__(256, 2) void caps_pass(
    const float* __restrict__ w, const unsigned short* __restrict__ xh,
    const unsigned short* __restrict__ xl, const float* __restrict__ V,
    float* __restrict__ part) {
    __shared__ unsigned short sh[2][128 * 64];  // hi plane, [col][i]
    __shared__ unsigned short sl[2][128 * 64];  // lo plane

    const int t = threadIdx.x;
    const int l = t & 63, wv = t >> 6;
    const int ch = blockIdx.x, ot = blockIdx.y;
    const int obase = ot * 4;
    const int kg = l >> 4;          // k-group (0..3)
    const int lm = l & 15;
    const int n0 = ch * CHN;

    // persistent per-lane V (pass1/2): V[b][c][o] for 4 b-rows x 8 c x 1 o
    float Vreg[8][4];
    if constexpr (MODE == 1) {
#pragma unroll
        for (int t8 = 0; t8 < 8; ++t8)
#pragma unroll
            for (int r = 0; r < 4; ++r) {
                int b = 16 * wv + 4 * kg + r;
                int c = 4 * t8 + ((l >> 2) & 3);
                int o = obase + (l & 3);
                Vreg[t8][r] = V[((size_t)b * Cc + c) * Oo + o];
            }
    }
    float accs[8][4];
#pragma unroll
    for (int t8 = 0; t8 < 8; ++t8)
#pragma unroll
        for (int r = 0; r < 4; ++r) accs[t8][r] = 0.f;

    // staging: thread handles 8 chunks of 4 f32; col = (t>>4)+16k, i0 fixed
    const int i0 = (t & 15) * 4;
    const int colb = t >> 4;
    float4 ld[8];

    auto issue = [&](int n) {
#pragma unroll
        for (int k = 0; k < 8; ++k) {
            int col = colb + 16 * k;
            int c = col >> 2, ol = col & 3;
            const float* g =
                w + (((size_t)c * Nn + n) * Oo + obase + ol) * Ii + i0;
            ld[k] = *(const float4*)g;
        }
    };
    auto writebuf = [&](int buf) {
#pragma unroll
        for (int k = 0; k < 8; ++k) {
            int col = colb + 16 * k;
            int off = col * 64 + i0;
            float a[4] = {ld[k].x, ld[k].y, ld[k].z, ld[k].w};
            ushort4 H, L;
            unsigned short* hp = (unsigned short*)&H;
            unsigned short* lp = (unsigned short*)&L;
#pragma unroll
            for (int e = 0; e < 4; ++e) {
                unsigned short hb = bf16_rne(a[e]);
                hp[e] = hb;
                lp[e] = bf16_rne(a[e] - bf16_f(hb));
            }
            *(ushort4*)(&sh[buf][off]) = H;
            *(ushort4*)(&sl[buf][off]) = L;
        }
    };

    issue(n0);
    writebuf(0);
    __syncthreads();

    for (int j = 0; j < CHN; ++j) {
        const int n = n0 + j, cur = j & 1;
        if (j + 1 < CHN) issue(n0 + j + 1);

        // A-frags (x pre-split): lane row b = 16*wv + lm, k = q*32 + kg*8
        const size_t xoff = ((size_t)(16 * wv + lm) * Nn + n) * Ii + kg * 8;
        short8v ah0 = *(const short8v*)(xh + xoff);
        short8v al0 = *(const short8v*)(xl + xoff);
        short8v ah1 = *(const short8v*)(xh + xoff + 32);
        short8v al1 = *(const short8v*)(xl + xoff + 32);

        float u[8][4];
#pragma unroll
        for (int t8 = 0; t8 < 8; ++t8) {
            int coff = (16 * t8 + lm) * 64 + kg * 8;
            short8v bh0 = *(const short8v*)(&sh[cur][coff]);
            short8v bl0 = *(const short8v*)(&sl[cur][coff]);
            short8v bh1 = *(const short8v*)(&sh[cur][coff + 32]);
            short8v bl1 = *(const short8v*)(&sl[cur][coff + 32]);
            float4v a = {0.f, 0.f, 0.f, 0.f};
            a = __builtin_amdgcn_mfma_f32_16x16x32_bf16(ah0, bh0, a, 0, 0, 0);
            a = __builtin_amdgcn_mfma_f32_16x16x32_bf16(al0, bh0, a, 0, 0, 0);
            a = __builtin_amdgcn_mfma_f32_16x16x32_bf16(ah0, bl0, a, 0, 0, 0);
            a = __builtin_amdgcn_mfma_f32_16x16x32_bf16(ah1, bh1, a, 0, 0, 0);
            a = __builtin_amdgcn_mfma_f32_16x16x32_bf16(al1, bh1, a, 0, 0, 0);
            a = __builtin_amdgcn_mfma_f32_16x16x32_bf16(ah1, bl1, a, 0, 0, 0);
            u[t8][0] = a[0]; u[t8][1] = a[1]; u[t8][2] = a[2]; u[t8][3] = a[3];
        }

        if constexpr (MODE == 0) {
#pragma unroll
            for (int t8 = 0; t8 < 8; ++t8)
#pragma unroll
                for (int r = 0; r < 4; ++r) accs[t8][r] += u[t8][r];
        } else {
            // softmax over 32 c = 8 in-lane (t8) x 4 lanes (xor 4, 8)
#pragma unroll
            for (int r = 0; r < 4; ++r) {
                float m = -1e30f;
#pragma unroll
                for (int t8 = 0; t8 < 8; ++t8)
                    m = fmaxf(m, u[t8][r] * Vreg[t8][r]);
                m = fmaxf(m, __shfl_xor(m, 4));
                m = fmaxf(m, __shfl_xor(m, 8));
                float Z = 0.f;
#pragma unroll
                for (int t8 = 0; t8 < 8; ++t8) {
                    float e = __expf(u[t8][r] * Vreg[t8][r] - m);
                    Z += e;
                    u[t8][r] *= e;  // u now holds e*u
                }
                Z += __shfl_xor(Z, 4);
                Z += __shfl_xor(Z, 8);
                float rz = 1.f / Z;
#pragma unroll
                for (int t8 = 0; t8 < 8; ++t8) accs[t8][r] += u[t8][r] * rz;
            }
        }

        if (j + 1 < CHN) {
            writebuf(cur ^ 1);
            __syncthreads();
        }
    }

    // write per-chunk partials: part[ch][b][c][o]
#pragma unroll
    for (int t8 = 0; t8 < 8; ++t8)
#pragma unroll
        for (int r = 0; r < 4; ++r) {
            int b = 16 * wv + 4 * kg + r;
            int c = 4 * t8 + ((l >> 2) & 3);
            int o = obase + (l & 3);
            part[(((size_t)ch * Bb + b) * Cc + c) * Oo + o] = accs[t8][r];
        }
}

// ---- reduce partials over chunks; squash; update V / write out -------------
__global__ void reduce_caps(const float* __restrict__ part,
                            float* __restrict__ V, float* __restrict__ out,
                            int mode) {
    int bc = blockIdx.x;       // b*32+c, 2048 blocks
    int o = threadIdx.x;       // 64
    size_t base = (size_t)bc * 64 + o;
    float s = 0.f;
    for (int c = 0; c < NCH; ++c) s += part[(size_t)c * (Bb * Cc * Oo) + base];
    if (mode == 0)      V[base] = squash_elem(s * (1.f / 32.f));
    else if (mode == 1) V[base] += squash_elem(s);
    else                out[base] = squash_elem(s);
}

extern "C" void kernel_launch(void* const* d_in, const int* in_sizes, int n_in,
                              void* d_out, int out_size, void* d_ws, size_t ws_size,
                              hipStream_t stream) {
    const float* x = (const float*)d_in[0];          // [64,1152,64]
    const float* w = (const float*)d_in[1];          // [32,1152,64,64]
    float* out = (float*)d_out;                      // [64,32,64]

    const size_t XE = (size_t)Bb * Nn * Ii;          // 4,718,592
    unsigned short* xh = (unsigned short*)d_ws;
    unsigned short* xl = xh + XE;
    float* part = (float*)(xl + XE);                 // 32*64*32*64 f32
    float* V = part + (size_t)NCH * Bb * Cc * Oo;

    prep_x<<<(int)(XE / 4 / 256), 256, 0, stream>>>(x, xh, xl);

    caps_pass<0><<<dim3(NCH, OT), 256, 0, stream>>>(w, xh, xl, nullptr, part);
    reduce_caps<<<Bb * Cc, 64, 0, stream>>>(part, V, out, 0);   // V = v0
    caps_pass<1><<<dim3(NCH, OT), 256, 0, stream>>>(w, xh, xl, V, part);
    reduce_caps<<<Bb * Cc, 64, 0, stream>>>(part, V, out, 1);   // V += v1
    caps_pass<1><<<dim3(NCH, OT), 256, 0, stream>>>(w, xh, xl, V, part);
    reduce_caps<<<Bb * Cc, 64, 0, stream>>>(part, V, out, 2);   // out = v2
}